// Round 4
// baseline (663.163 us; speedup 1.0000x reference)
//
#include <hip/hip_runtime.h>
#include <hip/hip_bf16.h>
#include <math.h>

#define T_TOK   8192
#define D_MODEL 1024
#define DFFN    2048
#define N_EXP   8
#define NASSIGN (T_TOK*2)

#define BM 128
#define BN 128
#define BK 32
#define TILE_MAX 144

// ---- workspace layout (byte offsets) ----
#define WS_ZSUM     0        // float
#define WS_PSUM     4        // 8 floats
#define WS_COUNTS   64       // 8 ints
#define WS_CURSOR   96       // 8 ints
#define WS_OFFS     128      // 8 ints
#define WS_NTILES   160      // int
#define WS_TMAP     256      // TILE_MAX * 4 ints (e, gr, valid, pad)
#define WS_SEL      4096     // NASSIGN ints
#define WS_WGT      69632    // NASSIGN floats
#define WS_AIDX     135168   // NASSIGN ints
#define WS_AW       200704   // NASSIGN floats
#define WS_XB       266240                    // T_TOK*D_MODEL bf16   (16 MB)
#define WS_W1T      (WS_XB + 16777216)        // [e][n][k] bf16       (32 MB)
#define WS_W2T      (WS_W1T + 33554432)       // [e][n][k] bf16       (32 MB)
#define WS_H        (WS_W2T + 33554432)       // NASSIGN*DFFN bf16    (64 MB)

typedef __attribute__((ext_vector_type(8))) short bf16x8;
typedef __attribute__((ext_vector_type(4))) float f32x4;
typedef __attribute__((ext_vector_type(4))) unsigned int u32x4;

static __device__ __forceinline__ unsigned short f2bf(float f) {
    unsigned int u = __builtin_bit_cast(unsigned int, f);
    u += 0x7fffu + ((u >> 16) & 1u);
    return (unsigned short)(u >> 16);
}

// async global->LDS, 16B per lane; LDS side must be wave-base + lane*16.
static __device__ __forceinline__ void gll16(const unsigned short* g, unsigned short* l) {
    __builtin_amdgcn_global_load_lds(
        (const __attribute__((address_space(1))) unsigned int*)g,
        (__attribute__((address_space(3))) unsigned int*)l, 16, 0, 0);
}

// in: [E][K][N] fp32 -> out: [E][N][K] bf16 (64x64 tiles)
__global__ __launch_bounds__(256) void transpose_cvt_kernel(
    const float* __restrict__ in, unsigned short* __restrict__ out, int K, int N)
{
    int e = blockIdx.z;
    const float* inp = in + (size_t)e * K * N;
    unsigned short* outp = out + (size_t)e * K * N;
    __shared__ unsigned short tile[64][68];
    int k0 = blockIdx.y * 64, n0 = blockIdx.x * 64;
    int tid = threadIdx.x;
    int r = tid >> 4, c4 = (tid & 15) * 4;
    #pragma unroll
    for (int p = 0; p < 4; ++p) {
        int k = r + p * 16;
        float4 v = *(const float4*)(inp + (size_t)(k0 + k) * N + n0 + c4);
        tile[k][c4+0] = f2bf(v.x);
        tile[k][c4+1] = f2bf(v.y);
        tile[k][c4+2] = f2bf(v.z);
        tile[k][c4+3] = f2bf(v.w);
    }
    __syncthreads();
    int n = tid >> 2, kc = (tid & 3) * 16;
    unsigned short t[16];
    #pragma unroll
    for (int j = 0; j < 16; ++j) t[j] = tile[kc + j][n];
    unsigned short* o = outp + (size_t)(n0 + n) * K + k0 + kc;
    *(u32x4*)o       = *(u32x4*)t;
    *(u32x4*)(o + 8) = *(u32x4*)(t + 8);
}

// ---------------- router (fused x -> bf16 conversion) ----------------
__global__ __launch_bounds__(256) void router_kernel(
    const float* __restrict__ x, const float* __restrict__ rw,
    float* zsum, float* psum, int* counts, int* sel, float* wgt,
    unsigned short* __restrict__ xb)
{
    __shared__ float xs[32*129];
    __shared__ float rs[8*129];
    __shared__ float lg[32*9];
    __shared__ float blk_p[8];
    __shared__ int   blk_c[8];
    __shared__ float blk_z;
    int tid = threadIdx.x;
    if (tid < 8) { blk_p[tid] = 0.f; blk_c[tid] = 0; }
    if (tid == 8) blk_z = 0.f;
    int tb = blockIdx.x * 32;
    int tt = tid >> 3, e = tid & 7;
    float acc = 0.f;
    for (int c = 0; c < 8; ++c) {
        int c0 = c * 128;
        #pragma unroll
        for (int p = 0; p < 16; ++p) {
            int flat = p * 256 + tid;
            int r = flat >> 7, col = flat & 127;
            xs[r*129 + col] = x[(size_t)(tb + r)*D_MODEL + c0 + col];
        }
        #pragma unroll
        for (int p = 0; p < 4; ++p) {
            int flat = p * 256 + tid;
            int er = flat >> 7, col = flat & 127;
            rs[er*129 + col] = rw[(size_t)er*D_MODEL + c0 + col];
        }
        __syncthreads();
        {
            int rr = tid >> 3, cc = (tid & 7) * 16;
            unsigned short tmp[16];
            #pragma unroll
            for (int j = 0; j < 16; ++j) tmp[j] = f2bf(xs[rr*129 + cc + j]);
            unsigned short* o = xb + (size_t)(tb + rr)*D_MODEL + c0 + cc;
            *(u32x4*)o       = *(u32x4*)tmp;
            *(u32x4*)(o + 8) = *(u32x4*)(tmp + 8);
        }
        #pragma unroll 8
        for (int i = 0; i < 128; ++i)
            acc += xs[tt*129 + i] * rs[e*129 + i];
        __syncthreads();
    }
    lg[tt*9 + e] = acc;
    __syncthreads();
    if (tid < 32) {
        int t = tb + tid;
        float l[8], p[8];
        float mx = -1e30f;
        #pragma unroll
        for (int j = 0; j < 8; ++j) { l[j] = lg[tid*9 + j]; mx = fmaxf(mx, l[j]); }
        float se = 0.f;
        #pragma unroll
        for (int j = 0; j < 8; ++j) { p[j] = expf(l[j] - mx); se += p[j]; }
        float inv = 1.f / se;
        #pragma unroll
        for (int j = 0; j < 8; ++j) p[j] *= inv;
        float lse = mx + logf(se);
        atomicAdd(&blk_z, lse*lse);
        #pragma unroll
        for (int j = 0; j < 8; ++j) atomicAdd(&blk_p[j], p[j]);
        int i0 = 0; float b0 = p[0];
        #pragma unroll
        for (int j = 1; j < 8; ++j) if (p[j] > b0) { b0 = p[j]; i0 = j; }
        int i1 = -1; float b1 = -1.f;
        #pragma unroll
        for (int j = 0; j < 8; ++j) if (j != i0 && p[j] > b1) { b1 = p[j]; i1 = j; }
        float s = b0 + b1;
        sel[t*2+0] = i0; sel[t*2+1] = i1;
        wgt[t*2+0] = b0 / s; wgt[t*2+1] = b1 / s;
        atomicAdd(&blk_c[i0], 1); atomicAdd(&blk_c[i1], 1);
    }
    __syncthreads();
    if (tid < 8) {
        atomicAdd(&counts[tid], blk_c[tid]);
        unsafeAtomicAdd(&psum[tid], blk_p[tid]);
    }
    if (tid == 8) unsafeAtomicAdd(zsum, blk_z);
}

// ---------------- offsets + tile map + aux-loss scalars ----------------
__global__ void finalize_kernel(const int* counts, const float* psum, const float* zsum,
                                int* offs, int* ntiles, int* tmap, float* out_tail)
{
    if (threadIdx.x != 0) return;
    int off = 0, nt = 0;
    float lb = 0.f;
    for (int e = 0; e < N_EXP; ++e) {
        int c = counts[e];
        offs[e] = off;
        for (int m0 = 0; m0 < c; m0 += BM) {
            tmap[nt*4+0] = e;
            tmap[nt*4+1] = off + m0;
            tmap[nt*4+2] = min(BM, c - m0);
            tmap[nt*4+3] = 0;
            nt++;
        }
        float fi = (float)c / (float)NASSIGN;
        out_tail[2 + e] = fi;
        lb += fi * (psum[e] / (float)T_TOK);
        off += c;
    }
    *ntiles = nt;
    out_tail[0] = zsum[0] / (float)T_TOK;
    out_tail[1] = (float)N_EXP * lb;
}

// ---------------- scatter tokens into per-expert segments ----------------
__global__ __launch_bounds__(256) void scatter_kernel(
    const int* __restrict__ sel, const float* __restrict__ wgt,
    const int* __restrict__ offs, int* cursor, int* aidx, float* aw)
{
    int t = blockIdx.x * 256 + threadIdx.x;
    if (t >= T_TOK) return;
    #pragma unroll
    for (int k = 0; k < 2; ++k) {
        int e = sel[t*2 + k];
        int pos = atomicAdd(&cursor[e], 1);
        int r = offs[e] + pos;
        aidx[r] = t;
        aw[r] = wgt[t*2 + k];
    }
}

// ---------------- GEMM1: H = gelu(Xg @ W1_e), bf16 out ----------------
// BK=32, double-buffered LDS (chunk-major [kc][row]), raw-barrier pipeline.
__global__ __launch_bounds__(256) void gemm1_kernel(
    const unsigned short* __restrict__ xb, const unsigned short* __restrict__ w1t,
    const int* __restrict__ aidx, const int* __restrict__ tmap,
    const int* __restrict__ ntiles, unsigned short* __restrict__ H)
{
    // XCD-locality swizzle: gridDim.x=16 (n-blocks), y=TILE_MAX.
    int f = blockIdx.y * 16 + blockIdx.x;
    int xcd = f & 7, s = f >> 3;               // s in [0, 288)
    int tile = xcd * 18 + (s >> 4);            // 18 tiles per XCD slot
    int xblk = s & 15;
    if (tile >= *ntiles) return;
    int e     = tmap[tile*4+0];
    int gr    = tmap[tile*4+1];
    int valid = tmap[tile*4+2];
    int n0 = xblk * BN;
    __shared__ unsigned short As[2][4*128*8];   // [buf][kc*128+row][8] = 8 KB each
    __shared__ unsigned short Bs[2][4*128*8];
    int tid = threadIdx.x;
    int lane = tid & 63, wave = tid >> 6;
    int wm = (wave & 1) * 64, wn = (wave >> 1) * 64;
    int q = lane >> 4, r16 = lane & 15;
    f32x4 acc[4][4];
    #pragma unroll
    for (int i = 0; i < 4; ++i)
        #pragma unroll
        for (int j = 0; j < 4; ++j) acc[i][j] = (f32x4){0.f, 0.f, 0.f, 0.f};

    // staging: thread t handles row = t&127, kc halves (t>>7) and 2+(t>>7)
    int row = tid & 127, half = tid >> 7;
    int tok = aidx[gr + min(row, valid - 1)];
    const unsigned short* gA = xb + (size_t)tok * D_MODEL + half * 8;
    const unsigned short* gB = w1t + ((size_t)(e * DFFN + n0 + row)) * D_MODEL + half * 8;
    unsigned short* lA0[2]; unsigned short* lA1[2];
    unsigned short* lB0[2]; unsigned short* lB1[2];
    #pragma unroll
    for (int b = 0; b < 2; ++b) {
        lA0[b] = &As[b][(half*128 + row)*8];
        lA1[b] = &As[b][((2+half)*128 + row)*8];
        lB0[b] = &Bs[b][(half*128 + row)*8];
        lB1[b] = &Bs[b][((2+half)*128 + row)*8];
    }

    const int KT = D_MODEL / BK;   // 32
    // prologue
    gll16(gA, lA0[0]); gll16(gA + 16, lA1[0]);
    gll16(gB, lB0[0]); gll16(gB + 16, lB1[0]);
    for (int kt = 0; kt < KT; ++kt) {
        int b = kt & 1;
        if (kt + 1 < KT) {
            int ko = (kt + 1) * BK;
            gll16(gA + ko, lA0[b^1]); gll16(gA + ko + 16, lA1[b^1]);
            gll16(gB + ko, lB0[b^1]); gll16(gB + ko + 16, lB1[b^1]);
            asm volatile("s_waitcnt vmcnt(4)" ::: "memory");
        } else {
            asm volatile("s_waitcnt vmcnt(0)" ::: "memory");
        }
        asm volatile("s_barrier" ::: "memory");
        bf16x8 af[4], bfr[4];
        #pragma unroll
        for (int im = 0; im < 4; ++im)
            af[im] = *(const bf16x8*)&As[b][(q*128 + wm + im*16 + r16)*8];
        #pragma unroll
        for (int in = 0; in < 4; ++in)
            bfr[in] = *(const bf16x8*)&Bs[b][(q*128 + wn + in*16 + r16)*8];
        #pragma unroll
        for (int im = 0; im < 4; ++im)
            #pragma unroll
            for (int in = 0; in < 4; ++in)
                acc[im][in] = __builtin_amdgcn_mfma_f32_16x16x32_bf16(af[im], bfr[in], acc[im][in], 0, 0, 0);
        if (kt + 1 < KT) asm volatile("s_barrier" ::: "memory");
    }
    #pragma unroll
    for (int im = 0; im < 4; ++im) {
        #pragma unroll
        for (int reg = 0; reg < 4; ++reg) {
            int m = wm + im*16 + q*4 + reg;
            if (m < valid) {
                size_t rowbase = (size_t)(gr + m) * DFFN + n0 + wn;
                #pragma unroll
                for (int in = 0; in < 4; ++in) {
                    float v = acc[im][in][reg];
                    float g = 0.5f * v * (1.0f + erff(v * 0.70710678118654752f));
                    H[rowbase + in*16 + r16] = f2bf(g);
                }
            }
        }
    }
}

// ---------------- GEMM2: out[t] += w * (H_row @ W2_e) ----------------
__global__ __launch_bounds__(256) void gemm2_kernel(
    const unsigned short* __restrict__ H, const unsigned short* __restrict__ w2t,
    const int* __restrict__ aidx, const float* __restrict__ aw,
    const int* __restrict__ tmap, const int* __restrict__ ntiles,
    float* __restrict__ out)
{
    int f = blockIdx.y * 8 + blockIdx.x;
    int xcd = f & 7, s = f >> 3;               // s in [0, 144)
    int tile = xcd * 18 + (s >> 3);
    int xblk = s & 7;
    if (tile >= *ntiles) return;
    int e     = tmap[tile*4+0];
    int gr    = tmap[tile*4+1];
    int valid = tmap[tile*4+2];
    int n0 = xblk * BN;
    __shared__ unsigned short As[2][4*128*8];
    __shared__ unsigned short Bs[2][4*128*8];
    int tid = threadIdx.x;
    int lane = tid & 63, wave = tid >> 6;
    int wm = (wave & 1) * 64, wn = (wave >> 1) * 64;
    int q = lane >> 4, r16 = lane & 15;
    f32x4 acc[4][4];
    #pragma unroll
    for (int i = 0; i < 4; ++i)
        #pragma unroll
        for (int j = 0; j < 4; ++j) acc[i][j] = (f32x4){0.f, 0.f, 0.f, 0.f};

    int row = tid & 127, half = tid >> 7;
    const unsigned short* gA = H + (size_t)(gr + min(row, valid - 1)) * DFFN + half * 8;
    const unsigned short* gB = w2t + (size_t)e * (DFFN * D_MODEL) + (size_t)(n0 + row) * DFFN + half * 8;
    unsigned short* lA0[2]; unsigned short* lA1[2];
    unsigned short* lB0[2]; unsigned short* lB1[2];
    #pragma unroll
    for (int b = 0; b < 2; ++b) {
        lA0[b] = &As[b][(half*128 + row)*8];
        lA1[b] = &As[b][((2+half)*128 + row)*8];
        lB0[b] = &Bs[b][(half*128 + row)*8];
        lB1[b] = &Bs[b][((2+half)*128 + row)*8];
    }

    const int KT = DFFN / BK;   // 64
    gll16(gA, lA0[0]); gll16(gA + 16, lA1[0]);
    gll16(gB, lB0[0]); gll16(gB + 16, lB1[0]);
    for (int kt = 0; kt < KT; ++kt) {
        int b = kt & 1;
        if (kt + 1 < KT) {
            int ko = (kt + 1) * BK;
            gll16(gA + ko, lA0[b^1]); gll16(gA + ko + 16, lA1[b^1]);
            gll16(gB + ko, lB0[b^1]); gll16(gB + ko + 16, lB1[b^1]);
            asm volatile("s_waitcnt vmcnt(4)" ::: "memory");
        } else {
            asm volatile("s_waitcnt vmcnt(0)" ::: "memory");
        }
        asm volatile("s_barrier" ::: "memory");
        bf16x8 af[4], bfr[4];
        #pragma unroll
        for (int im = 0; im < 4; ++im)
            af[im] = *(const bf16x8*)&As[b][(q*128 + wm + im*16 + r16)*8];
        #pragma unroll
        for (int in = 0; in < 4; ++in)
            bfr[in] = *(const bf16x8*)&Bs[b][(q*128 + wn + in*16 + r16)*8];
        #pragma unroll
        for (int im = 0; im < 4; ++im)
            #pragma unroll
            for (int in = 0; in < 4; ++in)
                acc[im][in] = __builtin_amdgcn_mfma_f32_16x16x32_bf16(af[im], bfr[in], acc[im][in], 0, 0, 0);
        if (kt + 1 < KT) asm volatile("s_barrier" ::: "memory");
    }
    #pragma unroll
    for (int im = 0; im < 4; ++im) {
        #pragma unroll
        for (int reg = 0; reg < 4; ++reg) {
            int m = wm + im*16 + q*4 + reg;
            if (m < valid) {
                int t = aidx[gr + m];
                float w = aw[gr + m];
                float* orow = out + (size_t)t*D_MODEL + n0 + wn;
                #pragma unroll
                for (int in = 0; in < 4; ++in)
                    unsafeAtomicAdd(&orow[in*16 + r16], w * acc[im][in][reg]);
            }
        }
    }
}

extern "C" void kernel_launch(void* const* d_in, const int* in_sizes, int n_in,
                              void* d_out, int out_size, void* d_ws, size_t ws_size,
                              hipStream_t stream)
{
    const float* x  = (const float*)d_in[0];
    const float* rw = (const float*)d_in[1];
    const float* w1 = (const float*)d_in[2];
    const float* w2 = (const float*)d_in[3];
    float* out = (float*)d_out;
    char* ws = (char*)d_ws;
    float* zsum   = (float*)(ws + WS_ZSUM);
    float* psum   = (float*)(ws + WS_PSUM);
    int*   counts = (int*)(ws + WS_COUNTS);
    int*   cursor = (int*)(ws + WS_CURSOR);
    int*   offs   = (int*)(ws + WS_OFFS);
    int*   ntiles = (int*)(ws + WS_NTILES);
    int*   tmap   = (int*)(ws + WS_TMAP);
    int*   sel    = (int*)(ws + WS_SEL);
    float* wgt    = (float*)(ws + WS_WGT);
    int*   aidx   = (int*)(ws + WS_AIDX);
    float* aw     = (float*)(ws + WS_AW);
    unsigned short* xb  = (unsigned short*)(ws + WS_XB);
    unsigned short* w1t = (unsigned short*)(ws + WS_W1T);
    unsigned short* w2t = (unsigned short*)(ws + WS_W2T);
    unsigned short* H   = (unsigned short*)(ws + WS_H);

    hipMemsetAsync(d_out, 0, (size_t)T_TOK * D_MODEL * sizeof(float), stream);
    hipMemsetAsync(ws, 0, 256, stream);

    // W1: [K=1024][E*N=16384] -> [16384][1024]
    transpose_cvt_kernel<<<dim3(16384/64, 1024/64, 1), 256, 0, stream>>>(w1, w1t, 1024, 16384);
    // W2: per expert [K=2048][N=1024] -> [1024][2048]
    transpose_cvt_kernel<<<dim3(1024/64, 2048/64, 8), 256, 0, stream>>>(w2, w2t, 2048, 1024);

    router_kernel<<<T_TOK/32, 256, 0, stream>>>(x, rw, zsum, psum, counts, sel, wgt, xb);
    finalize_kernel<<<1, 64, 0, stream>>>(counts, psum, zsum, offs, ntiles, tmap,
                                          out + (size_t)T_TOK * D_MODEL);
    scatter_kernel<<<T_TOK/256, 256, 0, stream>>>(sel, wgt, offs, cursor, aidx, aw);
    gemm1_kernel<<<dim3(16, TILE_MAX), 256, 0, stream>>>(xb, w1t, aidx, tmap, ntiles, H);
    gemm2_kernel<<<dim3(8, TILE_MAX), 256, 0, stream>>>(H, w2t, aidx, aw, tmap, ntiles, out);
}

// Round 5
// 656.446 us; speedup vs baseline: 1.0102x; 1.0102x over previous
//
#include <hip/hip_runtime.h>
#include <hip/hip_bf16.h>
#include <math.h>

#define T_TOK   8192
#define D_MODEL 1024
#define DFFN    2048
#define N_EXP   8
#define NASSIGN (T_TOK*2)

#define BM 128
#define BN 128
#define BK 32
#define TILE_MAX 144

// ---- workspace layout (byte offsets) ----
#define WS_ZSUM     0        // float
#define WS_PSUM     4        // 8 floats
#define WS_COUNTS   64       // 8 ints
#define WS_CURSOR   96       // 8 ints
#define WS_OFFS     128      // 8 ints
#define WS_NTILES   160      // int
#define WS_TMAP     256      // TILE_MAX * 4 ints (e, gr, valid, pad)
#define WS_SEL      4096     // NASSIGN ints
#define WS_WGT      69632    // NASSIGN floats
#define WS_AIDX     135168   // NASSIGN ints
#define WS_AW       200704   // NASSIGN floats
#define WS_XB       266240                    // T_TOK*D_MODEL bf16   (16 MB)
#define WS_W1T      (WS_XB + 16777216)        // [e][n][k] bf16       (32 MB)
#define WS_W2T      (WS_W1T + 33554432)       // [e][n][k] bf16       (32 MB)
#define WS_H        (WS_W2T + 33554432)       // NASSIGN*DFFN bf16    (64 MB)

typedef __attribute__((ext_vector_type(8))) short bf16x8;
typedef __attribute__((ext_vector_type(4))) float f32x4;
typedef __attribute__((ext_vector_type(4))) unsigned int u32x4;

static __device__ __forceinline__ unsigned short f2bf(float f) {
    unsigned int u = __builtin_bit_cast(unsigned int, f);
    u += 0x7fffu + ((u >> 16) & 1u);
    return (unsigned short)(u >> 16);
}

// async global->LDS, 16B per lane; LDS side must be wave-base + lane*16.
static __device__ __forceinline__ void gll16(const unsigned short* g, unsigned short* l) {
    __builtin_amdgcn_global_load_lds(
        (const __attribute__((address_space(1))) unsigned int*)g,
        (__attribute__((address_space(3))) unsigned int*)l, 16, 0, 0);
}

// in: [E][K][N] fp32 -> out: [E][N][K] bf16 (64x64 tiles)
__global__ __launch_bounds__(256) void transpose_cvt_kernel(
    const float* __restrict__ in, unsigned short* __restrict__ out, int K, int N)
{
    int e = blockIdx.z;
    const float* inp = in + (size_t)e * K * N;
    unsigned short* outp = out + (size_t)e * K * N;
    __shared__ unsigned short tile[64][68];
    int k0 = blockIdx.y * 64, n0 = blockIdx.x * 64;
    int tid = threadIdx.x;
    int r = tid >> 4, c4 = (tid & 15) * 4;
    #pragma unroll
    for (int p = 0; p < 4; ++p) {
        int k = r + p * 16;
        float4 v = *(const float4*)(inp + (size_t)(k0 + k) * N + n0 + c4);
        tile[k][c4+0] = f2bf(v.x);
        tile[k][c4+1] = f2bf(v.y);
        tile[k][c4+2] = f2bf(v.z);
        tile[k][c4+3] = f2bf(v.w);
    }
    __syncthreads();
    int n = tid >> 2, kc = (tid & 3) * 16;
    unsigned short t[16];
    #pragma unroll
    for (int j = 0; j < 16; ++j) t[j] = tile[kc + j][n];
    unsigned short* o = outp + (size_t)(n0 + n) * K + k0 + kc;
    *(u32x4*)o       = *(u32x4*)t;
    *(u32x4*)(o + 8) = *(u32x4*)(t + 8);
}

// ---------------- router (fused x -> bf16 conversion) ----------------
__global__ __launch_bounds__(256) void router_kernel(
    const float* __restrict__ x, const float* __restrict__ rw,
    float* zsum, float* psum, int* counts, int* sel, float* wgt,
    unsigned short* __restrict__ xb)
{
    __shared__ float xs[32*129];
    __shared__ float rs[8*129];
    __shared__ float lg[32*9];
    __shared__ float blk_p[8];
    __shared__ int   blk_c[8];
    __shared__ float blk_z;
    int tid = threadIdx.x;
    if (tid < 8) { blk_p[tid] = 0.f; blk_c[tid] = 0; }
    if (tid == 8) blk_z = 0.f;
    int tb = blockIdx.x * 32;
    int tt = tid >> 3, e = tid & 7;
    float acc = 0.f;
    for (int c = 0; c < 8; ++c) {
        int c0 = c * 128;
        #pragma unroll
        for (int p = 0; p < 16; ++p) {
            int flat = p * 256 + tid;
            int r = flat >> 7, col = flat & 127;
            xs[r*129 + col] = x[(size_t)(tb + r)*D_MODEL + c0 + col];
        }
        #pragma unroll
        for (int p = 0; p < 4; ++p) {
            int flat = p * 256 + tid;
            int er = flat >> 7, col = flat & 127;
            rs[er*129 + col] = rw[(size_t)er*D_MODEL + c0 + col];
        }
        __syncthreads();
        {
            int rr = tid >> 3, cc = (tid & 7) * 16;
            unsigned short tmp[16];
            #pragma unroll
            for (int j = 0; j < 16; ++j) tmp[j] = f2bf(xs[rr*129 + cc + j]);
            unsigned short* o = xb + (size_t)(tb + rr)*D_MODEL + c0 + cc;
            *(u32x4*)o       = *(u32x4*)tmp;
            *(u32x4*)(o + 8) = *(u32x4*)(tmp + 8);
        }
        #pragma unroll 8
        for (int i = 0; i < 128; ++i)
            acc += xs[tt*129 + i] * rs[e*129 + i];
        __syncthreads();
    }
    lg[tt*9 + e] = acc;
    __syncthreads();
    if (tid < 32) {
        int t = tb + tid;
        float l[8], p[8];
        float mx = -1e30f;
        #pragma unroll
        for (int j = 0; j < 8; ++j) { l[j] = lg[tid*9 + j]; mx = fmaxf(mx, l[j]); }
        float se = 0.f;
        #pragma unroll
        for (int j = 0; j < 8; ++j) { p[j] = expf(l[j] - mx); se += p[j]; }
        float inv = 1.f / se;
        #pragma unroll
        for (int j = 0; j < 8; ++j) p[j] *= inv;
        float lse = mx + logf(se);
        atomicAdd(&blk_z, lse*lse);
        #pragma unroll
        for (int j = 0; j < 8; ++j) atomicAdd(&blk_p[j], p[j]);
        int i0 = 0; float b0 = p[0];
        #pragma unroll
        for (int j = 1; j < 8; ++j) if (p[j] > b0) { b0 = p[j]; i0 = j; }
        int i1 = -1; float b1 = -1.f;
        #pragma unroll
        for (int j = 0; j < 8; ++j) if (j != i0 && p[j] > b1) { b1 = p[j]; i1 = j; }
        float s = b0 + b1;
        sel[t*2+0] = i0; sel[t*2+1] = i1;
        wgt[t*2+0] = b0 / s; wgt[t*2+1] = b1 / s;
        atomicAdd(&blk_c[i0], 1); atomicAdd(&blk_c[i1], 1);
    }
    __syncthreads();
    if (tid < 8) {
        atomicAdd(&counts[tid], blk_c[tid]);
        unsafeAtomicAdd(&psum[tid], blk_p[tid]);
    }
    if (tid == 8) unsafeAtomicAdd(zsum, blk_z);
}

// ---------------- offsets + tile map + aux-loss scalars ----------------
__global__ void finalize_kernel(const int* counts, const float* psum, const float* zsum,
                                int* offs, int* ntiles, int* tmap, float* out_tail)
{
    if (threadIdx.x != 0) return;
    int off = 0, nt = 0;
    float lb = 0.f;
    for (int e = 0; e < N_EXP; ++e) {
        int c = counts[e];
        offs[e] = off;
        for (int m0 = 0; m0 < c; m0 += BM) {
            tmap[nt*4+0] = e;
            tmap[nt*4+1] = off + m0;
            tmap[nt*4+2] = min(BM, c - m0);
            tmap[nt*4+3] = 0;
            nt++;
        }
        float fi = (float)c / (float)NASSIGN;
        out_tail[2 + e] = fi;
        lb += fi * (psum[e] / (float)T_TOK);
        off += c;
    }
    *ntiles = nt;
    out_tail[0] = zsum[0] / (float)T_TOK;
    out_tail[1] = (float)N_EXP * lb;
}

// ---------------- scatter tokens into per-expert segments ----------------
__global__ __launch_bounds__(256) void scatter_kernel(
    const int* __restrict__ sel, const float* __restrict__ wgt,
    const int* __restrict__ offs, int* cursor, int* aidx, float* aw)
{
    int t = blockIdx.x * 256 + threadIdx.x;
    if (t >= T_TOK) return;
    #pragma unroll
    for (int k = 0; k < 2; ++k) {
        int e = sel[t*2 + k];
        int pos = atomicAdd(&cursor[e], 1);
        int r = offs[e] + pos;
        aidx[r] = t;
        aw[r] = wgt[t*2 + k];
    }
}

// ---------------- GEMM1: H = gelu(Xg @ W1_e), bf16 out ----------------
// Plain 2-barrier K-loop (BK=32), chunk-major [kc][row] LDS, XCD tile swizzle.
__global__ __launch_bounds__(256) void gemm1_kernel(
    const unsigned short* __restrict__ xb, const unsigned short* __restrict__ w1t,
    const int* __restrict__ aidx, const int* __restrict__ tmap,
    const int* __restrict__ ntiles, unsigned short* __restrict__ H)
{
    // XCD-locality swizzle: all 16 n-blocks of a row-tile (and 18 consecutive
    // tiles) land on one XCD -> B slab + gathered A rows are L2-resident.
    int f = blockIdx.y * 16 + blockIdx.x;
    int xcd = f & 7, s = f >> 3;               // s in [0, 288)
    int tile = xcd * 18 + (s >> 4);
    int xblk = s & 15;
    if (tile >= *ntiles) return;
    int e     = tmap[tile*4+0];
    int gr    = tmap[tile*4+1];
    int valid = tmap[tile*4+2];
    int n0 = xblk * BN;
    __shared__ unsigned short As[4*128*8];     // [kc][row][8] = 8 KB
    __shared__ unsigned short Bs[4*128*8];
    int tid = threadIdx.x;
    int lane = tid & 63, wave = tid >> 6;
    int wm = (wave & 1) * 64, wn = (wave >> 1) * 64;
    int q = lane >> 4, r16 = lane & 15;
    f32x4 acc[4][4];
    #pragma unroll
    for (int i = 0; i < 4; ++i)
        #pragma unroll
        for (int j = 0; j < 4; ++j) acc[i][j] = (f32x4){0.f, 0.f, 0.f, 0.f};

    // staging: thread t handles row = t&127, k-chunks half and 2+half
    int row = tid & 127, half = tid >> 7;
    int tok = aidx[gr + min(row, valid - 1)];
    const unsigned short* gA = xb + (size_t)tok * D_MODEL + half * 8;
    const unsigned short* gB = w1t + ((size_t)(e * DFFN + n0 + row)) * D_MODEL + half * 8;
    unsigned short* lA0 = &As[(half*128 + row)*8];
    unsigned short* lA1 = &As[((2+half)*128 + row)*8];
    unsigned short* lB0 = &Bs[(half*128 + row)*8];
    unsigned short* lB1 = &Bs[((2+half)*128 + row)*8];

    for (int kt = 0; kt < D_MODEL / BK; ++kt) {
        int ko = kt * BK;
        gll16(gA + ko, lA0); gll16(gA + ko + 16, lA1);
        gll16(gB + ko, lB0); gll16(gB + ko + 16, lB1);
        __syncthreads();
        bf16x8 af[4], bfr[4];
        #pragma unroll
        for (int im = 0; im < 4; ++im)
            af[im] = *(const bf16x8*)&As[(q*128 + wm + im*16 + r16)*8];
        #pragma unroll
        for (int in = 0; in < 4; ++in)
            bfr[in] = *(const bf16x8*)&Bs[(q*128 + wn + in*16 + r16)*8];
        #pragma unroll
        for (int im = 0; im < 4; ++im)
            #pragma unroll
            for (int in = 0; in < 4; ++in)
                acc[im][in] = __builtin_amdgcn_mfma_f32_16x16x32_bf16(af[im], bfr[in], acc[im][in], 0, 0, 0);
        __syncthreads();
    }
    #pragma unroll
    for (int im = 0; im < 4; ++im) {
        #pragma unroll
        for (int reg = 0; reg < 4; ++reg) {
            int m = wm + im*16 + q*4 + reg;
            if (m < valid) {
                size_t rowbase = (size_t)(gr + m) * DFFN + n0 + wn;
                #pragma unroll
                for (int in = 0; in < 4; ++in) {
                    float v = acc[im][in][reg];
                    float g = 0.5f * v * (1.0f + erff(v * 0.70710678118654752f));
                    H[rowbase + in*16 + r16] = f2bf(g);
                }
            }
        }
    }
}

// ---------------- GEMM2: out[t] += w * (H_row @ W2_e) ----------------
__global__ __launch_bounds__(256) void gemm2_kernel(
    const unsigned short* __restrict__ H, const unsigned short* __restrict__ w2t,
    const int* __restrict__ aidx, const float* __restrict__ aw,
    const int* __restrict__ tmap, const int* __restrict__ ntiles,
    float* __restrict__ out)
{
    int f = blockIdx.y * 8 + blockIdx.x;
    int xcd = f & 7, s = f >> 3;               // s in [0, 144)
    int tile = xcd * 18 + (s >> 3);
    int xblk = s & 7;
    if (tile >= *ntiles) return;
    int e     = tmap[tile*4+0];
    int gr    = tmap[tile*4+1];
    int valid = tmap[tile*4+2];
    int n0 = xblk * BN;
    __shared__ unsigned short As[4*128*8];
    __shared__ unsigned short Bs[4*128*8];
    int tid = threadIdx.x;
    int lane = tid & 63, wave = tid >> 6;
    int wm = (wave & 1) * 64, wn = (wave >> 1) * 64;
    int q = lane >> 4, r16 = lane & 15;
    f32x4 acc[4][4];
    #pragma unroll
    for (int i = 0; i < 4; ++i)
        #pragma unroll
        for (int j = 0; j < 4; ++j) acc[i][j] = (f32x4){0.f, 0.f, 0.f, 0.f};

    int row = tid & 127, half = tid >> 7;
    const unsigned short* gA = H + (size_t)(gr + min(row, valid - 1)) * DFFN + half * 8;
    const unsigned short* gB = w2t + (size_t)e * (DFFN * D_MODEL) + (size_t)(n0 + row) * DFFN + half * 8;
    unsigned short* lA0 = &As[(half*128 + row)*8];
    unsigned short* lA1 = &As[((2+half)*128 + row)*8];
    unsigned short* lB0 = &Bs[(half*128 + row)*8];
    unsigned short* lB1 = &Bs[((2+half)*128 + row)*8];

    for (int kt = 0; kt < DFFN / BK; ++kt) {
        int ko = kt * BK;
        gll16(gA + ko, lA0); gll16(gA + ko + 16, lA1);
        gll16(gB + ko, lB0); gll16(gB + ko + 16, lB1);
        __syncthreads();
        bf16x8 af[4], bfr[4];
        #pragma unroll
        for (int im = 0; im < 4; ++im)
            af[im] = *(const bf16x8*)&As[(q*128 + wm + im*16 + r16)*8];
        #pragma unroll
        for (int in = 0; in < 4; ++in)
            bfr[in] = *(const bf16x8*)&Bs[(q*128 + wn + in*16 + r16)*8];
        #pragma unroll
        for (int im = 0; im < 4; ++im)
            #pragma unroll
            for (int in = 0; in < 4; ++in)
                acc[im][in] = __builtin_amdgcn_mfma_f32_16x16x32_bf16(af[im], bfr[in], acc[im][in], 0, 0, 0);
        __syncthreads();
    }
    #pragma unroll
    for (int im = 0; im < 4; ++im) {
        #pragma unroll
        for (int reg = 0; reg < 4; ++reg) {
            int m = wm + im*16 + q*4 + reg;
            if (m < valid) {
                int t = aidx[gr + m];
                float w = aw[gr + m];
                float* orow = out + (size_t)t*D_MODEL + n0 + wn;
                #pragma unroll
                for (int in = 0; in < 4; ++in)
                    unsafeAtomicAdd(&orow[in*16 + r16], w * acc[im][in][reg]);
            }
        }
    }
}

extern "C" void kernel_launch(void* const* d_in, const int* in_sizes, int n_in,
                              void* d_out, int out_size, void* d_ws, size_t ws_size,
                              hipStream_t stream)
{
    const float* x  = (const float*)d_in[0];
    const float* rw = (const float*)d_in[1];
    const float* w1 = (const float*)d_in[2];
    const float* w2 = (const float*)d_in[3];
    float* out = (float*)d_out;
    char* ws = (char*)d_ws;
    float* zsum   = (float*)(ws + WS_ZSUM);
    float* psum   = (float*)(ws + WS_PSUM);
    int*   counts = (int*)(ws + WS_COUNTS);
    int*   cursor = (int*)(ws + WS_CURSOR);
    int*   offs   = (int*)(ws + WS_OFFS);
    int*   ntiles = (int*)(ws + WS_NTILES);
    int*   tmap   = (int*)(ws + WS_TMAP);
    int*   sel    = (int*)(ws + WS_SEL);
    float* wgt    = (float*)(ws + WS_WGT);
    int*   aidx   = (int*)(ws + WS_AIDX);
    float* aw     = (float*)(ws + WS_AW);
    unsigned short* xb  = (unsigned short*)(ws + WS_XB);
    unsigned short* w1t = (unsigned short*)(ws + WS_W1T);
    unsigned short* w2t = (unsigned short*)(ws + WS_W2T);
    unsigned short* H   = (unsigned short*)(ws + WS_H);

    hipMemsetAsync(d_out, 0, (size_t)T_TOK * D_MODEL * sizeof(float), stream);
    hipMemsetAsync(ws, 0, 256, stream);

    // W1: [K=1024][E*N=16384] -> [16384][1024]
    transpose_cvt_kernel<<<dim3(16384/64, 1024/64, 1), 256, 0, stream>>>(w1, w1t, 1024, 16384);
    // W2: per expert [K=2048][N=1024] -> [1024][2048]
    transpose_cvt_kernel<<<dim3(1024/64, 2048/64, 8), 256, 0, stream>>>(w2, w2t, 2048, 1024);

    router_kernel<<<T_TOK/32, 256, 0, stream>>>(x, rw, zsum, psum, counts, sel, wgt, xb);
    finalize_kernel<<<1, 64, 0, stream>>>(counts, psum, zsum, offs, ntiles, tmap,
                                          out + (size_t)T_TOK * D_MODEL);
    scatter_kernel<<<T_TOK/256, 256, 0, stream>>>(sel, wgt, offs, cursor, aidx, aw);
    gemm1_kernel<<<dim3(16, TILE_MAX), 256, 0, stream>>>(xb, w1t, aidx, tmap, ntiles, H);
    gemm2_kernel<<<dim3(8, TILE_MAX), 256, 0, stream>>>(H, w2t, aidx, aw, tmap, ntiles, out);
}